// Round 14
// baseline (321.476 us; speedup 1.0000x reference)
//
#include <hip/hip_runtime.h>
#include <math.h>

static constexpr int BTOT = 32768;
static constexpr int IND  = 64;
static constexpr int HD   = 256;
static constexpr int LT   = 32;
static constexpr int NCH  = 8;
static constexpr int NCD  = 256;
static constexpr int TM   = 32;          // r10 geometry (proven optimum)
static constexpr int NBLK = BTOT / TM;   // 1024

// workspace float offsets
static constexpr int WS_M    = 0;        // 8*256 folded score matrix M = cq@Wk
static constexpr int WS_C0   = 2048;     // 8 folded score bias c0 = cq@bk
static constexpr int WS_CSQ  = 2056;     // 8*256 codebook squared norms
static constexpr int WS_PART = 4104;     // NBLK loss partials (1024)
static constexpr int WS_W1T  = 8192;     // 64 x 256  W1 transposed
static constexpr int WS_W2T  = 24576;    // 256 x 256 W2 transposed
static constexpr int WS_WVT  = 90112;    // 256 x 32  Wv transposed
static constexpr int WS_CBH  = 98304;    // 65536 ushorts: codebook bf16 hi
static constexpr int WS_CBL  = 131072;   // 65536 ushorts: codebook bf16 lo
// total ws: 163840 floats = 640 KB

// output float offsets
static constexpr long long O_KCHART = 0;
static constexpr long long O_KCODE  = 32768;
static constexpr long long O_ZN     = 65536;
static constexpr long long O_ZTEX   = 1114112;
static constexpr long long O_RW     = 2162688;
static constexpr long long O_ZGEO   = 2424832;
static constexpr long long O_VQ     = 3473408;
static constexpr long long O_IDX    = 3473409;
static constexpr long long O_ZNALL  = 3735553;

// Kernel A LDS: 8192 floats = 32 KB exactly. x(swz) -> h1 -> h2.
static constexpr int L_CH  = 0;

// Kernel B LDS: 2880 floats = 11.25 KB (r10 verbatim).
static constexpr int BL_V   = 0;
static constexpr int BL_W1  = 1152;
static constexpr int BL_W2T = 1728;
static constexpr int BL_B1  = 2304;
static constexpr int BL_B2  = 2320;
static constexpr int BL_SCR = 2352;   // 2 x 128 floats used (dbuf, float2 recs)
static constexpr int BL_MISC= 2864;
static constexpr int BLDS_F = 2880;

typedef __attribute__((ext_vector_type(8))) __bf16 bf16x8;
typedef __attribute__((ext_vector_type(4))) float  f32x4;

__device__ __forceinline__ float gelu_f(float x) {
    return 0.5f * x * (1.0f + erff(x * 0.70710678118654752f));
}
__device__ __forceinline__ float dot4(float4 a, float4 b) {
    return a.x * b.x + a.y * b.y + a.z * b.z + a.w * b.w;
}
__device__ __forceinline__ unsigned umn(unsigned a, unsigned b) { return a < b ? a : b; }
__device__ __forceinline__ unsigned umx(unsigned a, unsigned b) { return a > b ? a : b; }
// numpy pairwise_sum of squares, n=32
__device__ __forceinline__ float np_sumsq32(const float* a) {
#pragma clang fp contract(off)
    float r0 = a[0]*a[0],  r1 = a[1]*a[1],  r2 = a[2]*a[2],  r3 = a[3]*a[3];
    float r4 = a[4]*a[4],  r5 = a[5]*a[5],  r6 = a[6]*a[6],  r7 = a[7]*a[7];
    r0 += a[8]*a[8];   r1 += a[9]*a[9];   r2 += a[10]*a[10]; r3 += a[11]*a[11];
    r4 += a[12]*a[12]; r5 += a[13]*a[13]; r6 += a[14]*a[14]; r7 += a[15]*a[15];
    r0 += a[16]*a[16]; r1 += a[17]*a[17]; r2 += a[18]*a[18]; r3 += a[19]*a[19];
    r4 += a[20]*a[20]; r5 += a[21]*a[21]; r6 += a[22]*a[22]; r7 += a[23]*a[23];
    r0 += a[24]*a[24]; r1 += a[25]*a[25]; r2 += a[26]*a[26]; r3 += a[27]*a[27];
    r4 += a[28]*a[28]; r5 += a[29]*a[29]; r6 += a[30]*a[30]; r7 += a[31]*a[31];
    return ((r0 + r1) + (r2 + r3)) + ((r4 + r5) + (r6 + r7));
}

// hi/lo bf16 split (A-fragments only; B comes precomputed from prep)
__device__ __forceinline__ void split8(const float* f, bf16x8& hi, bf16x8& lo) {
    union U { unsigned short u[8]; bf16x8 v; };
    U h, l;
#pragma unroll
    for (int i = 0; i < 8; ++i) {
        const unsigned uf = __float_as_uint(f[i]);
        const float fl = f[i] - __uint_as_float(uf & 0xFFFF0000u);
        h.u[i] = (unsigned short)(uf >> 16);
        l.u[i] = (unsigned short)(__float_as_uint(fl) >> 16);
    }
    hi = h.v; lo = l.v;
}

// ---------- prep (73 blocks): M, c_sq, c0, W transposes, codebook bf16 split ----------
__global__ __launch_bounds__(256) void prep_kernel(
    const float* __restrict__ Wk, const float* __restrict__ bk,
    const float* __restrict__ cq, const float* __restrict__ cb,
    const float* __restrict__ W1, const float* __restrict__ W2,
    const float* __restrict__ Wv,
    float* __restrict__ ws)
{
    const int g = blockIdx.x;
    const int t = threadIdx.x;
    if (g < 8) {
        float acc = 0.f;
        for (int o = 0; o < HD; ++o)
            acc += cq[g * HD + o] * Wk[o * HD + t];
        ws[WS_M + g * HD + t] = acc;
    } else if (g < 16) {
        const int gg = g - 8;
        {
            const float* p = cb + (long long)((gg << 8) + t) * LT;
            float a[32];
#pragma unroll
            for (int d = 0; d < LT; ++d) a[d] = p[d];
            ws[WS_CSQ + (gg << 8) + t] = np_sumsq32(a);
        }
        {
            float p = cq[gg * HD + t] * bk[t];
#pragma unroll
            for (int off = 1; off < 64; off <<= 1) p += __shfl_xor(p, off, 64);
            __shared__ float red[4];
            if ((t & 63) == 0) red[t >> 6] = p;
            __syncthreads();
            if (t == 0) ws[WS_C0 + gg] = red[0] + red[1] + red[2] + red[3];
        }
    } else if (g < 48) {
        const int ob = 8 * (g - 16);
        for (int i = 0; i < 8; ++i) {
            const int o = ob + i;
            ws[WS_W2T + t * HD + o] = W2[o * HD + t];
        }
    } else if (g < 56) {
        const int ob = 32 * (g - 48);
        const int k = t & 63;
        for (int i = (t >> 6); i < 32; i += 4) {
            const int o = ob + i;
            ws[WS_W1T + k * HD + o] = W1[o * IND + k];
        }
    } else if (g == 56) {
        for (int o = 0; o < 32; ++o)
            ws[WS_WVT + t * 32 + o] = Wv[o * HD + t];
    } else {
        const int base = (g - 57) * 4096;
        unsigned short* cbh = (unsigned short*)(ws + WS_CBH);
        unsigned short* cbl = (unsigned short*)(ws + WS_CBL);
        for (int i = 0; i < 16; ++i) {
            const int e = base + t + 256 * i;
            const float f = cb[e];
            const unsigned uf = __float_as_uint(f);
            const float fl = f - __uint_as_float(uf & 0xFFFF0000u);
            cbh[e] = (unsigned short)(uf >> 16);
            cbl[e] = (unsigned short)(__float_as_uint(fl) >> 16);
        }
    }
}

// ---------- kernel A: r13 + deeper prefetch (GEMM1 1-deep, GEMM2 2-deep) ----------
// Row-halved inner loops keep hv live-set at 4 (VGPR budget: <=128 for 4 waves/SIMD).
// Per-accumulator FMA order stays k-ascending -> bit-identical.
__global__ __launch_bounds__(256) void main_kernel(
    const float* __restrict__ x,  const float* __restrict__ b1,
    const float* __restrict__ b2, const float* __restrict__ bv,
    const float* __restrict__ ws, float* __restrict__ out)
{
    __shared__ float lds[8192];
    const int tid = threadIdx.x;
    const int bid = blockIdx.x;
    const int r0  = bid * TM;
    const int co  = tid & 63;
    const int ro  = tid >> 6;
    const float* W1T = ws + WS_W1T;
    const float* W2T = ws + WS_W2T;
    const float* WvT = ws + WS_WVT;

    {
        const float4* xg = (const float4*)(x + (long long)r0 * IND);
        float4* xs = (float4*)&lds[L_CH];
#pragma unroll
        for (int i = 0; i < 2; ++i) {
            int f4 = tid + 256 * i;
            int row = f4 >> 4, q = f4 & 15;
            xs[row * 16 + (q ^ (row & 7))] = xg[f4];
        }
    }
    __syncthreads();

    float acc[8][4];

    // ---- GEMM1: h1 = gelu(x @ W1^T + b1), K=64; 1-deep W prefetch ----
#pragma unroll
    for (int i = 0; i < 8; ++i)
#pragma unroll
        for (int j = 0; j < 4; ++j) acc[i][j] = 0.f;
    {
        float4 c0 = *(const float4*)&W1T[0 * HD + 4 * co];
        float4 c1 = *(const float4*)&W1T[1 * HD + 4 * co];
        float4 c2 = *(const float4*)&W1T[2 * HD + 4 * co];
        float4 c3 = *(const float4*)&W1T[3 * HD + 4 * co];
        for (int kk = 0; kk < IND; kk += 4) {
            float4 n0 = c0, n1 = c1, n2 = c2, n3 = c3;
            if (kk + 4 < IND) {
                n0 = *(const float4*)&W1T[(kk + 4) * HD + 4 * co];
                n1 = *(const float4*)&W1T[(kk + 5) * HD + 4 * co];
                n2 = *(const float4*)&W1T[(kk + 6) * HD + 4 * co];
                n3 = *(const float4*)&W1T[(kk + 7) * HD + 4 * co];
            }
            const int kq = kk >> 2;
            float4 wvs[4];
            wvs[0] = make_float4(c0.x, c1.x, c2.x, c3.x);
            wvs[1] = make_float4(c0.y, c1.y, c2.y, c3.y);
            wvs[2] = make_float4(c0.z, c1.z, c2.z, c3.z);
            wvs[3] = make_float4(c0.w, c1.w, c2.w, c3.w);
#pragma unroll
            for (int h = 0; h < 2; ++h) {
                float4 hv[4];
#pragma unroll
                for (int i = 0; i < 4; ++i) {
                    const int row = 8 * ro + 4 * h + i;
                    hv[i] = *(const float4*)&lds[L_CH + row * IND + 4 * (kq ^ (4 * h + i))];
                }
#pragma unroll
                for (int j = 0; j < 4; ++j)
#pragma unroll
                    for (int i = 0; i < 4; ++i) acc[4 * h + i][j] += dot4(hv[i], wvs[j]);
            }
            c0 = n0; c1 = n1; c2 = n2; c3 = n3;
        }
    }
    __syncthreads();
    {
        float4 bb = *(const float4*)&b1[4 * co];
#pragma unroll
        for (int i = 0; i < 8; ++i) {
            float4 h;
            h.x = gelu_f(acc[i][0] + bb.x);
            h.y = gelu_f(acc[i][1] + bb.y);
            h.z = gelu_f(acc[i][2] + bb.z);
            h.w = gelu_f(acc[i][3] + bb.w);
            *(float4*)&lds[L_CH + (8 * ro + i) * HD + 4 * (co ^ i)] = h;
        }
    }
    __syncthreads();

    // ---- GEMM2: h2 = gelu(h1 @ W2^T + b2), K=256; 2-deep W prefetch ----
#pragma unroll
    for (int i = 0; i < 8; ++i)
#pragma unroll
        for (int j = 0; j < 4; ++j) acc[i][j] = 0.f;
    {
        float4 c0 = *(const float4*)&W2T[0 * HD + 4 * co];
        float4 c1 = *(const float4*)&W2T[1 * HD + 4 * co];
        float4 c2 = *(const float4*)&W2T[2 * HD + 4 * co];
        float4 c3 = *(const float4*)&W2T[3 * HD + 4 * co];
        float4 d0 = *(const float4*)&W2T[4 * HD + 4 * co];
        float4 d1 = *(const float4*)&W2T[5 * HD + 4 * co];
        float4 d2 = *(const float4*)&W2T[6 * HD + 4 * co];
        float4 d3 = *(const float4*)&W2T[7 * HD + 4 * co];
        for (int kk = 0; kk < HD; kk += 4) {
            float4 g0 = d0, g1 = d1, g2 = d2, g3 = d3;
            if (kk + 8 < HD) {
                g0 = *(const float4*)&W2T[(kk + 8)  * HD + 4 * co];
                g1 = *(const float4*)&W2T[(kk + 9)  * HD + 4 * co];
                g2 = *(const float4*)&W2T[(kk + 10) * HD + 4 * co];
                g3 = *(const float4*)&W2T[(kk + 11) * HD + 4 * co];
            }
            const int kq = kk >> 2;
            float4 wvs[4];
            wvs[0] = make_float4(c0.x, c1.x, c2.x, c3.x);
            wvs[1] = make_float4(c0.y, c1.y, c2.y, c3.y);
            wvs[2] = make_float4(c0.z, c1.z, c2.z, c3.z);
            wvs[3] = make_float4(c0.w, c1.w, c2.w, c3.w);
#pragma unroll
            for (int h = 0; h < 2; ++h) {
                float4 hv[4];
#pragma unroll
                for (int i = 0; i < 4; ++i) {
                    const int row = 8 * ro + 4 * h + i;
                    hv[i] = *(const float4*)&lds[L_CH + row * HD + 4 * (kq ^ (4 * h + i))];
                }
#pragma unroll
                for (int j = 0; j < 4; ++j)
#pragma unroll
                    for (int i = 0; i < 4; ++i) acc[4 * h + i][j] += dot4(hv[i], wvs[j]);
            }
            c0 = d0; c1 = d1; c2 = d2; c3 = d3;
            d0 = g0; d1 = g1; d2 = g2; d3 = g3;
        }
    }
    __syncthreads();
    {
        float4 bb = *(const float4*)&b2[4 * co];
#pragma unroll
        for (int i = 0; i < 8; ++i) {
            float4 h;
            h.x = gelu_f(acc[i][0] + bb.x);
            h.y = gelu_f(acc[i][1] + bb.y);
            h.z = gelu_f(acc[i][2] + bb.z);
            h.w = gelu_f(acc[i][3] + bb.w);
            *(float4*)&lds[L_CH + (8 * ro + i) * HD + 4 * (co ^ i)] = h;
        }
    }
    __syncthreads();

    // ---- phase 3: scores + v; Wv/M prefetched 1 iter ahead (r13 verbatim) ----
    const int r  = tid >> 3;
    const int s  = tid & 7;
    const int rx = r & 7;
    const long long b = r0 + r;

    float  accS = 0.f;
    float4 accV; accV.x = accV.y = accV.z = accV.w = 0.f;
    const float* Mrow = ws + WS_M + s * HD;
    {
        float4 mv = *(const float4*)&Mrow[0];
        float4 w0 = *(const float4*)&WvT[0 * 32 + 4 * s];
        float4 w1 = *(const float4*)&WvT[1 * 32 + 4 * s];
        float4 w2 = *(const float4*)&WvT[2 * 32 + 4 * s];
        float4 w3 = *(const float4*)&WvT[3 * 32 + 4 * s];
        for (int k4 = 0; k4 < 64; ++k4) {
            float4 nm = mv, n0 = w0, n1 = w1, n2 = w2, n3 = w3;
            if (k4 + 1 < 64) {
                nm = *(const float4*)&Mrow[4 * (k4 + 1)];
                n0 = *(const float4*)&WvT[(4 * k4 + 4) * 32 + 4 * s];
                n1 = *(const float4*)&WvT[(4 * k4 + 5) * 32 + 4 * s];
                n2 = *(const float4*)&WvT[(4 * k4 + 6) * 32 + 4 * s];
                n3 = *(const float4*)&WvT[(4 * k4 + 7) * 32 + 4 * s];
            }
            float4 hv = *(const float4*)&lds[L_CH + r * HD + 4 * (k4 ^ rx)];
            accS += dot4(hv, mv);
            float4 q0 = make_float4(w0.x, w1.x, w2.x, w3.x);
            float4 q1 = make_float4(w0.y, w1.y, w2.y, w3.y);
            float4 q2 = make_float4(w0.z, w1.z, w2.z, w3.z);
            float4 q3 = make_float4(w0.w, w1.w, w2.w, w3.w);
            accV.x += dot4(hv, q0);
            accV.y += dot4(hv, q1);
            accV.z += dot4(hv, q2);
            accV.w += dot4(hv, q3);
            mv = nm; w0 = n0; w1 = n1; w2 = n2; w3 = n3;
        }
    }

    {
        float4 bb = *(const float4*)&bv[4 * s];
        float4 vv;
        vv.x = accV.x + bb.x; vv.y = accV.y + bb.y;
        vv.z = accV.z + bb.z; vv.w = accV.w + bb.w;
        *(float4*)&out[O_ZTEX + b * 32 + 4 * s] = vv;
    }

    float score = (accS + ws[WS_C0 + s]) * (1.0f / 16.0f);
    float mx = score;
    mx = fmaxf(mx, __shfl_xor(mx, 1, 64));
    mx = fmaxf(mx, __shfl_xor(mx, 2, 64));
    mx = fmaxf(mx, __shfl_xor(mx, 4, 64));
    float e = expf(score - mx);
    float sm = e;
    sm += __shfl_xor(sm, 1, 64);
    sm += __shfl_xor(sm, 2, 64);
    sm += __shfl_xor(sm, 4, 64);
    out[O_RW + b * 8 + s] = e / sm;
    float av = e; int ai = s;
    {
        float ov; int oi;
        ov = __shfl_xor(av, 1, 64); oi = __shfl_xor(ai, 1, 64);
        if (ov > av || (ov == av && oi < ai)) { av = ov; ai = oi; }
        ov = __shfl_xor(av, 2, 64); oi = __shfl_xor(ai, 2, 64);
        if (ov > av || (ov == av && oi < ai)) { av = ov; ai = oi; }
        ov = __shfl_xor(av, 4, 64); oi = __shfl_xor(ai, 4, 64);
        if (ov > av || (ov == av && oi < ai)) { av = ov; ai = oi; }
    }
    if (s == 0) out[O_KCHART + b] = (float)ai;
}

// ---------- kernel B: VQ chart loop (r10 verbatim; packed top-2 scan) ----------
__global__ __launch_bounds__(256) void chart_kernel(
    const float* __restrict__ cb,
    const float* __restrict__ Ws1, const float* __restrict__ bs1,
    const float* __restrict__ Ws2, const float* __restrict__ bs2,
    const float* __restrict__ ws, float* __restrict__ out, float* __restrict__ wspart)
{
    __shared__ float lds[BLDS_F];
    const int tid = threadIdx.x;
    const int bid = blockIdx.x;
    const int r0  = bid * TM;
    const int r   = tid >> 3;
    const int s   = tid & 7;
    const long long b = r0 + r;

#pragma unroll
    for (int it = 0; it < 2; ++it) {
        int idx = tid + 256 * it;
        lds[BL_W1  + (idx >> 5) * 36 + (idx & 31)] = Ws1[idx];
        lds[BL_W2T + (idx & 15) * 36 + (idx >> 4)] = Ws2[idx];
    }
    if (tid < 16) lds[BL_B1 + tid] = bs1[tid];
    if (tid < 32) lds[BL_B2 + tid] = bs2[tid];
    const float4 vs = *(const float4*)&out[O_ZTEX + b * 32 + 4 * s];
    *(float4*)&lds[BL_V + r * 36 + 4 * (s ^ (r & 7))] = vs;
    const float w_reg = out[O_RW + b * 8 + s];
    const int kchart  = (int)out[O_KCHART + b];
    __syncthreads();

    if (s == 0) {
        float vr[32];
#pragma unroll
        for (int q = 0; q < 8; ++q) {
            float4 t4 = *(const float4*)&lds[BL_V + r * 36 + 4 * (q ^ (r & 7))];
            vr[4 * q + 0] = t4.x; vr[4 * q + 1] = t4.y;
            vr[4 * q + 2] = t4.z; vr[4 * q + 3] = t4.w;
        }
        lds[BL_V + r * 36 + 32] = np_sumsq32(vr);
    }

    const int lane = tid & 63;
    const int wvi  = tid >> 6;
    const int mw   = wvi & 1;
    const int hw   = wvi >> 1;
    const int lcol = lane & 15;
    const int lks  = lane >> 4;
    bf16x8 ahf, alf;
    {
        const int R = 16 * mw + lcol;
        float f[8];
        *(float4*)&f[0] = *(const float4*)&lds[BL_V + R * 36 + 4 * ((2 * lks) ^ (R & 7))];
        *(float4*)&f[4] = *(const float4*)&lds[BL_V + R * 36 + 4 * (((2 * lks) | 1) ^ (R & 7))];
        split8(f, ahf, alf);
    }
    __syncthreads();
    const float vsq32 = lds[BL_V + r * 36 + 32];

    const unsigned short* cbhU = (const unsigned short*)(ws + WS_CBH);
    const unsigned short* cblU = (const unsigned short*)(ws + WS_CBL);

    float4 zqb; zqb.x = zqb.y = zqb.z = zqb.w = 0.f;
    float4 zn4; zn4.x = zn4.y = zn4.z = zn4.w = 0.f;
    float lossAcc = 0.f;
    int kcode = 0;

    for (int n = 0; n < NCH; ++n) {
        const float* cbn  = cb + (long long)n * (NCD * LT);
        const float* csqA = ws + WS_CSQ + (n << 8);

        // ---- MFMA approx scan; top-2 over packed keys (dist-bits | code-idx) ----
        unsigned k1[4], k2[4];
#pragma unroll
        for (int j = 0; j < 4; ++j) { k1[j] = 0xFFFFFFFFu; k2[j] = 0xFFFFFFFFu; }
        const int ebase = ((n << 8) + 128 * hw + lcol) * 32 + 8 * lks;
        const float* csqn = csqA + 128 * hw + lcol;
#pragma unroll
        for (int t = 0; t < 8; ++t) {
            const int eoff = ebase + t * (16 * 32);
            bf16x8 bh = *(const bf16x8*)(cbhU + eoff);
            bf16x8 bl = *(const bf16x8*)(cblU + eoff);
            f32x4 ac = {0.f, 0.f, 0.f, 0.f};
            ac = __builtin_amdgcn_mfma_f32_16x16x32_bf16(ahf, bh, ac, 0, 0, 0);
            ac = __builtin_amdgcn_mfma_f32_16x16x32_bf16(alf, bh, ac, 0, 0, 0);
            ac = __builtin_amdgcn_mfma_f32_16x16x32_bf16(ahf, bl, ac, 0, 0, 0);
            const float cs = csqn[t * 16];
            const unsigned Ct = (unsigned)(128 * hw + t * 16 + lcol);
#pragma unroll
            for (int j = 0; j < 4; ++j) {
                float d = cs - 2.0f * ac[j];
                unsigned ub = (__float_as_uint(d) & 0xFFFFFF00u) | Ct;
                unsigned key = ub ^ ((unsigned)((int)ub >> 31) | 0x80000000u);
                k2[j] = umn(k2[j], umx(k1[j], key));
                k1[j] = umn(k1[j], key);
            }
        }
        // butterfly top-2 merge over the 16 code-lanes
#pragma unroll
        for (int off = 1; off < 16; off <<= 1) {
#pragma unroll
            for (int j = 0; j < 4; ++j) {
                unsigned o1 = (unsigned)__shfl_xor((int)k1[j], off, 64);
                unsigned o2 = (unsigned)__shfl_xor((int)k2[j], off, 64);
                k2[j] = umn(umn(k2[j], o2), umx(k1[j], o1));
                k1[j] = umn(k1[j], o1);
            }
        }
        // per-row half-results -> scratch (float2, double-buffered; 1 barrier/chart)
        const int scb = BL_SCR + (n & 1) * 256;
        if (lcol == 0) {
#pragma unroll
            for (int j = 0; j < 4; ++j) {
                const int R = 16 * mw + 4 * lks + j;
                float2 rec;
                rec.x = __uint_as_float(k1[j]);
                rec.y = __uint_as_float(k2[j]);
                *(float2*)&lds[scb + (R * 2 + hw) * 2] = rec;
            }
        }
        __syncthreads();

        // ---- merge halves -> candidate; exact re-eval (numerics unchanged) ----
        int bestC;
        {
            float2 h0 = *(const float2*)&lds[scb + (r * 2 + 0) * 2];
            float2 h1 = *(const float2*)&lds[scb + (r * 2 + 1) * 2];
            unsigned a1 = __float_as_uint(h0.x), a2 = __float_as_uint(h0.y);
            unsigned c1 = __float_as_uint(h1.x), c2 = __float_as_uint(h1.y);
            unsigned m1 = umn(a1, c1);
            unsigned m2 = umn(umn(a2, c2), umx(a1, c1));
            unsigned mk = (s & 1) ? m2 : m1;
            unsigned ubk = (mk & 0x80000000u) ? (mk ^ 0x80000000u) : ~mk;
            const int cand = (int)(ubk & 0xFFu);

            double cr = 0.0;
            const float4* pc = (const float4*)(cbn + cand * LT);
#pragma unroll
            for (int j = 0; j < 8; ++j) {
                float4 q = pc[j];
                float4 vq = *(const float4*)&lds[BL_V + r * 36 + 4 * (j ^ (r & 7))];
                cr += (double)vq.x * q.x + (double)vq.y * q.y
                    + (double)vq.z * q.z + (double)vq.w * q.w;
            }
            float cross32 = (float)cr;
            float dme;
            {
#pragma clang fp contract(off)
                dme = (vsq32 - 2.0f * cross32) + csqA[cand];
            }
            float dot_ = __shfl_xor(dme, 1, 64);
            int  candO = __shfl_xor(cand, 1, 64);
            bestC = ((dot_ < dme) || (dot_ == dme && candO < cand)) ? candO : cand;
        }

        if (s == 0) out[O_IDX + b * 8 + n] = (float)bestC;
        if (n == kchart) kcode = bestC;

        const float wn = __shfl(w_reg, (tid & 56) | n, 64);
        const float* pz = cbn + bestC * LT;

        {
            float4 zq = *(const float4*)(pz + 4 * s);
            float4 d4;
            d4.x = vs.x - zq.x; d4.y = vs.y - zq.y;
            d4.z = vs.z - zq.z; d4.w = vs.w - zq.w;
            lossAcc += wn * (d4.x * d4.x + d4.y * d4.y + d4.z * d4.z + d4.w * d4.w);
            zqb.x += wn * zq.x; zqb.y += wn * zq.y;
            zqb.z += wn * zq.z; zqb.w += wn * zq.w;
        }

        float s1a, s1b;
        {
            float a0 = lds[BL_B1 + s], a1 = lds[BL_B1 + s + 8];
#pragma unroll
            for (int q = 0; q < 8; ++q) {
                float4 zq = *(const float4*)(pz + 4 * q);
                float4 vq = *(const float4*)&lds[BL_V + r * 36 + 4 * (q ^ (r & 7))];
                float4 dq;
                dq.x = vq.x - zq.x; dq.y = vq.y - zq.y;
                dq.z = vq.z - zq.z; dq.w = vq.w - zq.w;
                float4 u0 = *(const float4*)&lds[BL_W1 + s * 36 + 4 * q];
                float4 u1 = *(const float4*)&lds[BL_W1 + (s + 8) * 36 + 4 * q];
                a0 += dot4(dq, u0);
                a1 += dot4(dq, u1);
            }
            s1a = gelu_f(a0);
            s1b = gelu_f(a1);
        }

        float4 zna = *(const float4*)&lds[BL_B2 + 4 * s];
        {
            const int base = tid & 56;
#pragma unroll
            for (int j = 0; j < 8; ++j) {
                float sj = __shfl(s1a, base | j, 64);
                float4 wj = *(const float4*)&lds[BL_W2T + j * 36 + 4 * s];
                zna.x += sj * wj.x; zna.y += sj * wj.y;
                zna.z += sj * wj.z; zna.w += sj * wj.w;
            }
#pragma unroll
            for (int j = 0; j < 8; ++j) {
                float sj = __shfl(s1b, base | j, 64);
                float4 wj = *(const float4*)&lds[BL_W2T + (j + 8) * 36 + 4 * s];
                zna.x += sj * wj.x; zna.y += sj * wj.y;
                zna.z += sj * wj.z; zna.w += sj * wj.w;
            }
        }
        zn4.x += wn * zna.x; zn4.y += wn * zna.y;
        zn4.z += wn * zna.z; zn4.w += wn * zna.w;
        *(float4*)&out[O_ZNALL + (b * 8 + n) * 32 + 4 * s] = zna;
    }

    {
        float4 zt, zg;
        zt.x = (vs.x - zqb.x) - zn4.x; zt.y = (vs.y - zqb.y) - zn4.y;
        zt.z = (vs.z - zqb.z) - zn4.z; zt.w = (vs.w - zqb.w) - zn4.w;
        zg.x = zqb.x + zn4.x; zg.y = zqb.y + zn4.y;
        zg.z = zqb.z + zn4.z; zg.w = zqb.w + zn4.w;
        *(float4*)&out[O_ZN   + b * 32 + 4 * s] = zn4;
        *(float4*)&out[O_ZTEX + b * 32 + 4 * s] = zt;
        *(float4*)&out[O_ZGEO + b * 32 + 4 * s] = zg;
        if (s == 0) out[O_KCODE + b] = (float)kcode;
    }

#pragma unroll
    for (int off = 1; off < 64; off <<= 1) lossAcc += __shfl_xor(lossAcc, off, 64);
    __syncthreads();
    if ((tid & 63) == 0) lds[BL_MISC + (tid >> 6)] = lossAcc;
    __syncthreads();
    if (tid == 0)
        wspart[bid] = lds[BL_MISC] + lds[BL_MISC+1] + lds[BL_MISC+2] + lds[BL_MISC+3];
}

// ---------- finalize vq_loss ----------
__global__ __launch_bounds__(256) void fin_kernel(const float* __restrict__ wspart,
                                                  float* __restrict__ out)
{
    const int t = threadIdx.x;
    float sum = 0.f;
    for (int i = t; i < NBLK; i += 256) sum += wspart[i];
#pragma unroll
    for (int off = 1; off < 64; off <<= 1) sum += __shfl_xor(sum, off, 64);
    __shared__ float red[4];
    if ((t & 63) == 0) red[t >> 6] = sum;
    __syncthreads();
    if (t == 0)
        out[O_VQ] = (red[0] + red[1] + red[2] + red[3]) * (1.25f / (32768.0f * 32.0f));
}

extern "C" void kernel_launch(void* const* d_in, const int* in_sizes, int n_in,
                              void* d_out, int out_size, void* d_ws, size_t ws_size,
                              hipStream_t stream)
{
    const float* x   = (const float*)d_in[0];
    const float* W1  = (const float*)d_in[1];
    const float* b1  = (const float*)d_in[2];
    const float* W2  = (const float*)d_in[3];
    const float* b2  = (const float*)d_in[4];
    const float* Wk  = (const float*)d_in[5];
    const float* bk  = (const float*)d_in[6];
    const float* cq  = (const float*)d_in[7];
    const float* Wv  = (const float*)d_in[8];
    const float* bv  = (const float*)d_in[9];
    const float* cb  = (const float*)d_in[10];
    const float* Ws1 = (const float*)d_in[11];
    const float* bs1 = (const float*)d_in[12];
    const float* Ws2 = (const float*)d_in[13];
    const float* bs2 = (const float*)d_in[14];
    float* out = (float*)d_out;
    float* ws  = (float*)d_ws;

    prep_kernel<<<73, 256, 0, stream>>>(Wk, bk, cq, cb, W1, W2, Wv, ws);
    main_kernel<<<NBLK, 256, 0, stream>>>(x, b1, b2, bv, ws, out);
    chart_kernel<<<NBLK, 256, 0, stream>>>(cb, Ws1, bs1, Ws2, bs2, ws, out, ws + WS_PART);
    fin_kernel<<<1, 256, 0, stream>>>(ws + WS_PART, out);
}

// Round 15
// 312.466 us; speedup vs baseline: 1.0288x; 1.0288x over previous
//
#include <hip/hip_runtime.h>
#include <math.h>

static constexpr int BTOT = 32768;
static constexpr int IND  = 64;
static constexpr int HD   = 256;
static constexpr int LT   = 32;
static constexpr int NCH  = 8;
static constexpr int NCD  = 256;
static constexpr int TM   = 32;          // r10 geometry (proven optimum)
static constexpr int NBLK = BTOT / TM;   // 1024

// workspace float offsets
static constexpr int WS_M    = 0;        // 8*256 folded score matrix M = cq@Wk
static constexpr int WS_C0   = 2048;     // 8 folded score bias c0 = cq@bk
static constexpr int WS_CSQ  = 2056;     // 8*256 codebook squared norms
static constexpr int WS_PART = 4104;     // NBLK loss partials (1024)
static constexpr int WS_W1T  = 8192;     // 64 x 256  W1 transposed
static constexpr int WS_W2T  = 24576;    // 256 x 256 W2 transposed
static constexpr int WS_WVT  = 90112;    // 256 x 32  Wv transposed
static constexpr int WS_CBH  = 98304;    // 65536 ushorts: codebook bf16 hi
static constexpr int WS_CBL  = 131072;   // 65536 ushorts: codebook bf16 lo
// total ws: 163840 floats = 640 KB

// output float offsets
static constexpr long long O_KCHART = 0;
static constexpr long long O_KCODE  = 32768;
static constexpr long long O_ZN     = 65536;
static constexpr long long O_ZTEX   = 1114112;
static constexpr long long O_RW     = 2162688;
static constexpr long long O_ZGEO   = 2424832;
static constexpr long long O_VQ     = 3473408;
static constexpr long long O_IDX    = 3473409;
static constexpr long long O_ZNALL  = 3735553;

// Kernel A LDS: 8192 floats = 32 KB exactly. x(swz) -> h1 -> h2.
static constexpr int L_CH  = 0;

// Kernel B LDS: 2880 floats = 11.25 KB (r10 verbatim).
static constexpr int BL_V   = 0;
static constexpr int BL_W1  = 1152;
static constexpr int BL_W2T = 1728;
static constexpr int BL_B1  = 2304;
static constexpr int BL_B2  = 2320;
static constexpr int BL_SCR = 2352;   // 2 x 128 floats used (dbuf, float2 recs)
static constexpr int BL_MISC= 2864;
static constexpr int BLDS_F = 2880;

typedef __attribute__((ext_vector_type(8))) __bf16 bf16x8;
typedef __attribute__((ext_vector_type(4))) float  f32x4;

__device__ __forceinline__ float gelu_f(float x) {
    return 0.5f * x * (1.0f + erff(x * 0.70710678118654752f));
}
__device__ __forceinline__ float dot4(float4 a, float4 b) {
    return a.x * b.x + a.y * b.y + a.z * b.z + a.w * b.w;
}
__device__ __forceinline__ unsigned umn(unsigned a, unsigned b) { return a < b ? a : b; }
__device__ __forceinline__ unsigned umx(unsigned a, unsigned b) { return a > b ? a : b; }
// numpy pairwise_sum of squares, n=32
__device__ __forceinline__ float np_sumsq32(const float* a) {
#pragma clang fp contract(off)
    float r0 = a[0]*a[0],  r1 = a[1]*a[1],  r2 = a[2]*a[2],  r3 = a[3]*a[3];
    float r4 = a[4]*a[4],  r5 = a[5]*a[5],  r6 = a[6]*a[6],  r7 = a[7]*a[7];
    r0 += a[8]*a[8];   r1 += a[9]*a[9];   r2 += a[10]*a[10]; r3 += a[11]*a[11];
    r4 += a[12]*a[12]; r5 += a[13]*a[13]; r6 += a[14]*a[14]; r7 += a[15]*a[15];
    r0 += a[16]*a[16]; r1 += a[17]*a[17]; r2 += a[18]*a[18]; r3 += a[19]*a[19];
    r4 += a[20]*a[20]; r5 += a[21]*a[21]; r6 += a[22]*a[22]; r7 += a[23]*a[23];
    r0 += a[24]*a[24]; r1 += a[25]*a[25]; r2 += a[26]*a[26]; r3 += a[27]*a[27];
    r4 += a[28]*a[28]; r5 += a[29]*a[29]; r6 += a[30]*a[30]; r7 += a[31]*a[31];
    return ((r0 + r1) + (r2 + r3)) + ((r4 + r5) + (r6 + r7));
}

// hi/lo bf16 split (A-fragments only; B comes precomputed from prep)
__device__ __forceinline__ void split8(const float* f, bf16x8& hi, bf16x8& lo) {
    union U { unsigned short u[8]; bf16x8 v; };
    U h, l;
#pragma unroll
    for (int i = 0; i < 8; ++i) {
        const unsigned uf = __float_as_uint(f[i]);
        const float fl = f[i] - __uint_as_float(uf & 0xFFFF0000u);
        h.u[i] = (unsigned short)(uf >> 16);
        l.u[i] = (unsigned short)(__float_as_uint(fl) >> 16);
    }
    hi = h.v; lo = l.v;
}

// ---------- prep (73 blocks): M, c_sq, c0, W transposes, codebook bf16 split ----------
__global__ __launch_bounds__(256) void prep_kernel(
    const float* __restrict__ Wk, const float* __restrict__ bk,
    const float* __restrict__ cq, const float* __restrict__ cb,
    const float* __restrict__ W1, const float* __restrict__ W2,
    const float* __restrict__ Wv,
    float* __restrict__ ws)
{
    const int g = blockIdx.x;
    const int t = threadIdx.x;
    if (g < 8) {
        float acc = 0.f;
        for (int o = 0; o < HD; ++o)
            acc += cq[g * HD + o] * Wk[o * HD + t];
        ws[WS_M + g * HD + t] = acc;
    } else if (g < 16) {
        const int gg = g - 8;
        {
            const float* p = cb + (long long)((gg << 8) + t) * LT;
            float a[32];
#pragma unroll
            for (int d = 0; d < LT; ++d) a[d] = p[d];
            ws[WS_CSQ + (gg << 8) + t] = np_sumsq32(a);
        }
        {
            float p = cq[gg * HD + t] * bk[t];
#pragma unroll
            for (int off = 1; off < 64; off <<= 1) p += __shfl_xor(p, off, 64);
            __shared__ float red[4];
            if ((t & 63) == 0) red[t >> 6] = p;
            __syncthreads();
            if (t == 0) ws[WS_C0 + gg] = red[0] + red[1] + red[2] + red[3];
        }
    } else if (g < 48) {
        const int ob = 8 * (g - 16);
        for (int i = 0; i < 8; ++i) {
            const int o = ob + i;
            ws[WS_W2T + t * HD + o] = W2[o * HD + t];
        }
    } else if (g < 56) {
        const int ob = 32 * (g - 48);
        const int k = t & 63;
        for (int i = (t >> 6); i < 32; i += 4) {
            const int o = ob + i;
            ws[WS_W1T + k * HD + o] = W1[o * IND + k];
        }
    } else if (g == 56) {
        for (int o = 0; o < 32; ++o)
            ws[WS_WVT + t * 32 + o] = Wv[o * HD + t];
    } else {
        const int base = (g - 57) * 4096;
        unsigned short* cbh = (unsigned short*)(ws + WS_CBH);
        unsigned short* cbl = (unsigned short*)(ws + WS_CBL);
        for (int i = 0; i < 16; ++i) {
            const int e = base + t + 256 * i;
            const float f = cb[e];
            const unsigned uf = __float_as_uint(f);
            const float fl = f - __uint_as_float(uf & 0xFFFF0000u);
            cbh[e] = (unsigned short)(uf >> 16);
            cbl[e] = (unsigned short)(__float_as_uint(fl) >> 16);
        }
    }
}

// ---------- kernel A: r13 verbatim (TM=32, transposed W, 1-deep prefetch) ----------
__global__ __launch_bounds__(256) void main_kernel(
    const float* __restrict__ x,  const float* __restrict__ b1,
    const float* __restrict__ b2, const float* __restrict__ bv,
    const float* __restrict__ ws, float* __restrict__ out)
{
    __shared__ float lds[8192];
    const int tid = threadIdx.x;
    const int bid = blockIdx.x;
    const int r0  = bid * TM;
    const int co  = tid & 63;
    const int ro  = tid >> 6;
    const float* W1T = ws + WS_W1T;
    const float* W2T = ws + WS_W2T;
    const float* WvT = ws + WS_WVT;

    {
        const float4* xg = (const float4*)(x + (long long)r0 * IND);
        float4* xs = (float4*)&lds[L_CH];
#pragma unroll
        for (int i = 0; i < 2; ++i) {
            int f4 = tid + 256 * i;
            int row = f4 >> 4, q = f4 & 15;
            xs[row * 16 + (q ^ (row & 7))] = xg[f4];
        }
    }
    __syncthreads();

    float acc[8][4];

    // ---- GEMM1: h1 = gelu(x @ W1^T + b1), K=64 (16 iters; unchanged) ----
#pragma unroll
    for (int i = 0; i < 8; ++i)
#pragma unroll
        for (int j = 0; j < 4; ++j) acc[i][j] = 0.f;
    for (int kk = 0; kk < IND; kk += 4) {
        const int kq = kk >> 2;
        float4 hv[8];
#pragma unroll
        for (int i = 0; i < 8; ++i)
            hv[i] = *(const float4*)&lds[L_CH + (8 * ro + i) * IND + 4 * (kq ^ i)];
        float4 t0 = *(const float4*)&W1T[(kk + 0) * HD + 4 * co];
        float4 t1 = *(const float4*)&W1T[(kk + 1) * HD + 4 * co];
        float4 t2 = *(const float4*)&W1T[(kk + 2) * HD + 4 * co];
        float4 t3 = *(const float4*)&W1T[(kk + 3) * HD + 4 * co];
        float4 wvs[4];
        wvs[0] = make_float4(t0.x, t1.x, t2.x, t3.x);
        wvs[1] = make_float4(t0.y, t1.y, t2.y, t3.y);
        wvs[2] = make_float4(t0.z, t1.z, t2.z, t3.z);
        wvs[3] = make_float4(t0.w, t1.w, t2.w, t3.w);
#pragma unroll
        for (int j = 0; j < 4; ++j)
#pragma unroll
            for (int i = 0; i < 8; ++i) acc[i][j] += dot4(hv[i], wvs[j]);
    }
    __syncthreads();
    {
        float4 bb = *(const float4*)&b1[4 * co];
#pragma unroll
        for (int i = 0; i < 8; ++i) {
            float4 h;
            h.x = gelu_f(acc[i][0] + bb.x);
            h.y = gelu_f(acc[i][1] + bb.y);
            h.z = gelu_f(acc[i][2] + bb.z);
            h.w = gelu_f(acc[i][3] + bb.w);
            *(float4*)&lds[L_CH + (8 * ro + i) * HD + 4 * (co ^ i)] = h;
        }
    }
    __syncthreads();

    // ---- GEMM2: h2 = gelu(h1 @ W2^T + b2), K=256; W prefetched 1 iter ahead ----
#pragma unroll
    for (int i = 0; i < 8; ++i)
#pragma unroll
        for (int j = 0; j < 4; ++j) acc[i][j] = 0.f;
    {
        float4 t0 = *(const float4*)&W2T[0 * HD + 4 * co];
        float4 t1 = *(const float4*)&W2T[1 * HD + 4 * co];
        float4 t2 = *(const float4*)&W2T[2 * HD + 4 * co];
        float4 t3 = *(const float4*)&W2T[3 * HD + 4 * co];
        for (int kk = 0; kk < HD; kk += 4) {
            float4 n0 = t0, n1 = t1, n2 = t2, n3 = t3;
            if (kk + 4 < HD) {
                n0 = *(const float4*)&W2T[(kk + 4) * HD + 4 * co];
                n1 = *(const float4*)&W2T[(kk + 5) * HD + 4 * co];
                n2 = *(const float4*)&W2T[(kk + 6) * HD + 4 * co];
                n3 = *(const float4*)&W2T[(kk + 7) * HD + 4 * co];
            }
            const int kq = kk >> 2;
            float4 hv[8];
#pragma unroll
            for (int i = 0; i < 8; ++i)
                hv[i] = *(const float4*)&lds[L_CH + (8 * ro + i) * HD + 4 * (kq ^ i)];
            float4 wvs[4];
            wvs[0] = make_float4(t0.x, t1.x, t2.x, t3.x);
            wvs[1] = make_float4(t0.y, t1.y, t2.y, t3.y);
            wvs[2] = make_float4(t0.z, t1.z, t2.z, t3.z);
            wvs[3] = make_float4(t0.w, t1.w, t2.w, t3.w);
#pragma unroll
            for (int j = 0; j < 4; ++j)
#pragma unroll
                for (int i = 0; i < 8; ++i) acc[i][j] += dot4(hv[i], wvs[j]);
            t0 = n0; t1 = n1; t2 = n2; t3 = n3;
        }
    }
    __syncthreads();
    {
        float4 bb = *(const float4*)&b2[4 * co];
#pragma unroll
        for (int i = 0; i < 8; ++i) {
            float4 h;
            h.x = gelu_f(acc[i][0] + bb.x);
            h.y = gelu_f(acc[i][1] + bb.y);
            h.z = gelu_f(acc[i][2] + bb.z);
            h.w = gelu_f(acc[i][3] + bb.w);
            *(float4*)&lds[L_CH + (8 * ro + i) * HD + 4 * (co ^ i)] = h;
        }
    }
    __syncthreads();

    // ---- phase 3: scores + v; Wv/M prefetched 1 iter ahead ----
    const int r  = tid >> 3;
    const int s  = tid & 7;
    const int rx = r & 7;
    const long long b = r0 + r;

    float  accS = 0.f;
    float4 accV; accV.x = accV.y = accV.z = accV.w = 0.f;
    const float* Mrow = ws + WS_M + s * HD;
    {
        float4 mv = *(const float4*)&Mrow[0];
        float4 w0 = *(const float4*)&WvT[0 * 32 + 4 * s];
        float4 w1 = *(const float4*)&WvT[1 * 32 + 4 * s];
        float4 w2 = *(const float4*)&WvT[2 * 32 + 4 * s];
        float4 w3 = *(const float4*)&WvT[3 * 32 + 4 * s];
        for (int k4 = 0; k4 < 64; ++k4) {
            float4 nm = mv, n0 = w0, n1 = w1, n2 = w2, n3 = w3;
            if (k4 + 1 < 64) {
                nm = *(const float4*)&Mrow[4 * (k4 + 1)];
                n0 = *(const float4*)&WvT[(4 * k4 + 4) * 32 + 4 * s];
                n1 = *(const float4*)&WvT[(4 * k4 + 5) * 32 + 4 * s];
                n2 = *(const float4*)&WvT[(4 * k4 + 6) * 32 + 4 * s];
                n3 = *(const float4*)&WvT[(4 * k4 + 7) * 32 + 4 * s];
            }
            float4 hv = *(const float4*)&lds[L_CH + r * HD + 4 * (k4 ^ rx)];
            accS += dot4(hv, mv);
            float4 q0 = make_float4(w0.x, w1.x, w2.x, w3.x);
            float4 q1 = make_float4(w0.y, w1.y, w2.y, w3.y);
            float4 q2 = make_float4(w0.z, w1.z, w2.z, w3.z);
            float4 q3 = make_float4(w0.w, w1.w, w2.w, w3.w);
            accV.x += dot4(hv, q0);
            accV.y += dot4(hv, q1);
            accV.z += dot4(hv, q2);
            accV.w += dot4(hv, q3);
            mv = nm; w0 = n0; w1 = n1; w2 = n2; w3 = n3;
        }
    }

    {
        float4 bb = *(const float4*)&bv[4 * s];
        float4 vv;
        vv.x = accV.x + bb.x; vv.y = accV.y + bb.y;
        vv.z = accV.z + bb.z; vv.w = accV.w + bb.w;
        *(float4*)&out[O_ZTEX + b * 32 + 4 * s] = vv;
    }

    float score = (accS + ws[WS_C0 + s]) * (1.0f / 16.0f);
    float mx = score;
    mx = fmaxf(mx, __shfl_xor(mx, 1, 64));
    mx = fmaxf(mx, __shfl_xor(mx, 2, 64));
    mx = fmaxf(mx, __shfl_xor(mx, 4, 64));
    float e = expf(score - mx);
    float sm = e;
    sm += __shfl_xor(sm, 1, 64);
    sm += __shfl_xor(sm, 2, 64);
    sm += __shfl_xor(sm, 4, 64);
    out[O_RW + b * 8 + s] = e / sm;
    float av = e; int ai = s;
    {
        float ov; int oi;
        ov = __shfl_xor(av, 1, 64); oi = __shfl_xor(ai, 1, 64);
        if (ov > av || (ov == av && oi < ai)) { av = ov; ai = oi; }
        ov = __shfl_xor(av, 2, 64); oi = __shfl_xor(ai, 2, 64);
        if (ov > av || (ov == av && oi < ai)) { av = ov; ai = oi; }
        ov = __shfl_xor(av, 4, 64); oi = __shfl_xor(ai, 4, 64);
        if (ov > av || (ov == av && oi < ai)) { av = ov; ai = oi; }
    }
    if (s == 0) out[O_KCHART + b] = (float)ai;
}

// ---------- kernel B: VQ chart loop (r10 verbatim; packed top-2 scan) ----------
__global__ __launch_bounds__(256) void chart_kernel(
    const float* __restrict__ cb,
    const float* __restrict__ Ws1, const float* __restrict__ bs1,
    const float* __restrict__ Ws2, const float* __restrict__ bs2,
    const float* __restrict__ ws, float* __restrict__ out, float* __restrict__ wspart)
{
    __shared__ float lds[BLDS_F];
    const int tid = threadIdx.x;
    const int bid = blockIdx.x;
    const int r0  = bid * TM;
    const int r   = tid >> 3;
    const int s   = tid & 7;
    const long long b = r0 + r;

#pragma unroll
    for (int it = 0; it < 2; ++it) {
        int idx = tid + 256 * it;
        lds[BL_W1  + (idx >> 5) * 36 + (idx & 31)] = Ws1[idx];
        lds[BL_W2T + (idx & 15) * 36 + (idx >> 4)] = Ws2[idx];
    }
    if (tid < 16) lds[BL_B1 + tid] = bs1[tid];
    if (tid < 32) lds[BL_B2 + tid] = bs2[tid];
    const float4 vs = *(const float4*)&out[O_ZTEX + b * 32 + 4 * s];
    *(float4*)&lds[BL_V + r * 36 + 4 * (s ^ (r & 7))] = vs;
    const float w_reg = out[O_RW + b * 8 + s];
    const int kchart  = (int)out[O_KCHART + b];
    __syncthreads();

    if (s == 0) {
        float vr[32];
#pragma unroll
        for (int q = 0; q < 8; ++q) {
            float4 t4 = *(const float4*)&lds[BL_V + r * 36 + 4 * (q ^ (r & 7))];
            vr[4 * q + 0] = t4.x; vr[4 * q + 1] = t4.y;
            vr[4 * q + 2] = t4.z; vr[4 * q + 3] = t4.w;
        }
        lds[BL_V + r * 36 + 32] = np_sumsq32(vr);
    }

    const int lane = tid & 63;
    const int wvi  = tid >> 6;
    const int mw   = wvi & 1;
    const int hw   = wvi >> 1;
    const int lcol = lane & 15;
    const int lks  = lane >> 4;
    bf16x8 ahf, alf;
    {
        const int R = 16 * mw + lcol;
        float f[8];
        *(float4*)&f[0] = *(const float4*)&lds[BL_V + R * 36 + 4 * ((2 * lks) ^ (R & 7))];
        *(float4*)&f[4] = *(const float4*)&lds[BL_V + R * 36 + 4 * (((2 * lks) | 1) ^ (R & 7))];
        split8(f, ahf, alf);
    }
    __syncthreads();
    const float vsq32 = lds[BL_V + r * 36 + 32];

    const unsigned short* cbhU = (const unsigned short*)(ws + WS_CBH);
    const unsigned short* cblU = (const unsigned short*)(ws + WS_CBL);

    float4 zqb; zqb.x = zqb.y = zqb.z = zqb.w = 0.f;
    float4 zn4; zn4.x = zn4.y = zn4.z = zn4.w = 0.f;
    float lossAcc = 0.f;
    int kcode = 0;

    for (int n = 0; n < NCH; ++n) {
        const float* cbn  = cb + (long long)n * (NCD * LT);
        const float* csqA = ws + WS_CSQ + (n << 8);

        // ---- MFMA approx scan; top-2 over packed keys (dist-bits | code-idx) ----
        unsigned k1[4], k2[4];
#pragma unroll
        for (int j = 0; j < 4; ++j) { k1[j] = 0xFFFFFFFFu; k2[j] = 0xFFFFFFFFu; }
        const int ebase = ((n << 8) + 128 * hw + lcol) * 32 + 8 * lks;
        const float* csqn = csqA + 128 * hw + lcol;
#pragma unroll
        for (int t = 0; t < 8; ++t) {
            const int eoff = ebase + t * (16 * 32);
            bf16x8 bh = *(const bf16x8*)(cbhU + eoff);
            bf16x8 bl = *(const bf16x8*)(cblU + eoff);
            f32x4 ac = {0.f, 0.f, 0.f, 0.f};
            ac = __builtin_amdgcn_mfma_f32_16x16x32_bf16(ahf, bh, ac, 0, 0, 0);
            ac = __builtin_amdgcn_mfma_f32_16x16x32_bf16(alf, bh, ac, 0, 0, 0);
            ac = __builtin_amdgcn_mfma_f32_16x16x32_bf16(ahf, bl, ac, 0, 0, 0);
            const float cs = csqn[t * 16];
            const unsigned Ct = (unsigned)(128 * hw + t * 16 + lcol);
#pragma unroll
            for (int j = 0; j < 4; ++j) {
                float d = cs - 2.0f * ac[j];
                unsigned ub = (__float_as_uint(d) & 0xFFFFFF00u) | Ct;
                unsigned key = ub ^ ((unsigned)((int)ub >> 31) | 0x80000000u);
                k2[j] = umn(k2[j], umx(k1[j], key));
                k1[j] = umn(k1[j], key);
            }
        }
        // butterfly top-2 merge over the 16 code-lanes
#pragma unroll
        for (int off = 1; off < 16; off <<= 1) {
#pragma unroll
            for (int j = 0; j < 4; ++j) {
                unsigned o1 = (unsigned)__shfl_xor((int)k1[j], off, 64);
                unsigned o2 = (unsigned)__shfl_xor((int)k2[j], off, 64);
                k2[j] = umn(umn(k2[j], o2), umx(k1[j], o1));
                k1[j] = umn(k1[j], o1);
            }
        }
        // per-row half-results -> scratch (float2, double-buffered; 1 barrier/chart)
        const int scb = BL_SCR + (n & 1) * 256;
        if (lcol == 0) {
#pragma unroll
            for (int j = 0; j < 4; ++j) {
                const int R = 16 * mw + 4 * lks + j;
                float2 rec;
                rec.x = __uint_as_float(k1[j]);
                rec.y = __uint_as_float(k2[j]);
                *(float2*)&lds[scb + (R * 2 + hw) * 2] = rec;
            }
        }
        __syncthreads();

        // ---- merge halves -> candidate; exact re-eval (numerics unchanged) ----
        int bestC;
        {
            float2 h0 = *(const float2*)&lds[scb + (r * 2 + 0) * 2];
            float2 h1 = *(const float2*)&lds[scb + (r * 2 + 1) * 2];
            unsigned a1 = __float_as_uint(h0.x), a2 = __float_as_uint(h0.y);
            unsigned c1 = __float_as_uint(h1.x), c2 = __float_as_uint(h1.y);
            unsigned m1 = umn(a1, c1);
            unsigned m2 = umn(umn(a2, c2), umx(a1, c1));
            unsigned mk = (s & 1) ? m2 : m1;
            unsigned ubk = (mk & 0x80000000u) ? (mk ^ 0x80000000u) : ~mk;
            const int cand = (int)(ubk & 0xFFu);

            double cr = 0.0;
            const float4* pc = (const float4*)(cbn + cand * LT);
#pragma unroll
            for (int j = 0; j < 8; ++j) {
                float4 q = pc[j];
                float4 vq = *(const float4*)&lds[BL_V + r * 36 + 4 * (j ^ (r & 7))];
                cr += (double)vq.x * q.x + (double)vq.y * q.y
                    + (double)vq.z * q.z + (double)vq.w * q.w;
            }
            float cross32 = (float)cr;
            float dme;
            {
#pragma clang fp contract(off)
                dme = (vsq32 - 2.0f * cross32) + csqA[cand];
            }
            float dot_ = __shfl_xor(dme, 1, 64);
            int  candO = __shfl_xor(cand, 1, 64);
            bestC = ((dot_ < dme) || (dot_ == dme && candO < cand)) ? candO : cand;
        }

        if (s == 0) out[O_IDX + b * 8 + n] = (float)bestC;
        if (n == kchart) kcode = bestC;

        const float wn = __shfl(w_reg, (tid & 56) | n, 64);
        const float* pz = cbn + bestC * LT;

        {
            float4 zq = *(const float4*)(pz + 4 * s);
            float4 d4;
            d4.x = vs.x - zq.x; d4.y = vs.y - zq.y;
            d4.z = vs.z - zq.z; d4.w = vs.w - zq.w;
            lossAcc += wn * (d4.x * d4.x + d4.y * d4.y + d4.z * d4.z + d4.w * d4.w);
            zqb.x += wn * zq.x; zqb.y += wn * zq.y;
            zqb.z += wn * zq.z; zqb.w += wn * zq.w;
        }

        float s1a, s1b;
        {
            float a0 = lds[BL_B1 + s], a1 = lds[BL_B1 + s + 8];
#pragma unroll
            for (int q = 0; q < 8; ++q) {
                float4 zq = *(const float4*)(pz + 4 * q);
                float4 vq = *(const float4*)&lds[BL_V + r * 36 + 4 * (q ^ (r & 7))];
                float4 dq;
                dq.x = vq.x - zq.x; dq.y = vq.y - zq.y;
                dq.z = vq.z - zq.z; dq.w = vq.w - zq.w;
                float4 u0 = *(const float4*)&lds[BL_W1 + s * 36 + 4 * q];
                float4 u1 = *(const float4*)&lds[BL_W1 + (s + 8) * 36 + 4 * q];
                a0 += dot4(dq, u0);
                a1 += dot4(dq, u1);
            }
            s1a = gelu_f(a0);
            s1b = gelu_f(a1);
        }

        float4 zna = *(const float4*)&lds[BL_B2 + 4 * s];
        {
            const int base = tid & 56;
#pragma unroll
            for (int j = 0; j < 8; ++j) {
                float sj = __shfl(s1a, base | j, 64);
                float4 wj = *(const float4*)&lds[BL_W2T + j * 36 + 4 * s];
                zna.x += sj * wj.x; zna.y += sj * wj.y;
                zna.z += sj * wj.z; zna.w += sj * wj.w;
            }
#pragma unroll
            for (int j = 0; j < 8; ++j) {
                float sj = __shfl(s1b, base | j, 64);
                float4 wj = *(const float4*)&lds[BL_W2T + (j + 8) * 36 + 4 * s];
                zna.x += sj * wj.x; zna.y += sj * wj.y;
                zna.z += sj * wj.z; zna.w += sj * wj.w;
            }
        }
        zn4.x += wn * zna.x; zn4.y += wn * zna.y;
        zn4.z += wn * zna.z; zn4.w += wn * zna.w;
        *(float4*)&out[O_ZNALL + (b * 8 + n) * 32 + 4 * s] = zna;
    }

    {
        float4 zt, zg;
        zt.x = (vs.x - zqb.x) - zn4.x; zt.y = (vs.y - zqb.y) - zn4.y;
        zt.z = (vs.z - zqb.z) - zn4.z; zt.w = (vs.w - zqb.w) - zn4.w;
        zg.x = zqb.x + zn4.x; zg.y = zqb.y + zn4.y;
        zg.z = zqb.z + zn4.z; zg.w = zqb.w + zn4.w;
        *(float4*)&out[O_ZN   + b * 32 + 4 * s] = zn4;
        *(float4*)&out[O_ZTEX + b * 32 + 4 * s] = zt;
        *(float4*)&out[O_ZGEO + b * 32 + 4 * s] = zg;
        if (s == 0) out[O_KCODE + b] = (float)kcode;
    }

#pragma unroll
    for (int off = 1; off < 64; off <<= 1) lossAcc += __shfl_xor(lossAcc, off, 64);
    __syncthreads();
    if ((tid & 63) == 0) lds[BL_MISC + (tid >> 6)] = lossAcc;
    __syncthreads();
    if (tid == 0)
        wspart[bid] = lds[BL_MISC] + lds[BL_MISC+1] + lds[BL_MISC+2] + lds[BL_MISC+3];
}

// ---------- finalize vq_loss ----------
__global__ __launch_bounds__(256) void fin_kernel(const float* __restrict__ wspart,
                                                  float* __restrict__ out)
{
    const int t = threadIdx.x;
    float sum = 0.f;
    for (int i = t; i < NBLK; i += 256) sum += wspart[i];
#pragma unroll
    for (int off = 1; off < 64; off <<= 1) sum += __shfl_xor(sum, off, 64);
    __shared__ float red[4];
    if ((t & 63) == 0) red[t >> 6] = sum;
    __syncthreads();
    if (t == 0)
        out[O_VQ] = (red[0] + red[1] + red[2] + red[3]) * (1.25f / (32768.0f * 32.0f));
}

extern "C" void kernel_launch(void* const* d_in, const int* in_sizes, int n_in,
                              void* d_out, int out_size, void* d_ws, size_t ws_size,
                              hipStream_t stream)
{
    const float* x   = (const float*)d_in[0];
    const float* W1  = (const float*)d_in[1];
    const float* b1  = (const float*)d_in[2];
    const float* W2  = (const float*)d_in[3];
    const float* b2  = (const float*)d_in[4];
    const float* Wk  = (const float*)d_in[5];
    const float* bk  = (const float*)d_in[6];
    const float* cq  = (const float*)d_in[7];
    const float* Wv  = (const float*)d_in[8];
    const float* bv  = (const float*)d_in[9];
    const float* cb  = (const float*)d_in[10];
    const float* Ws1 = (const float*)d_in[11];
    const float* bs1 = (const float*)d_in[12];
    const float* Ws2 = (const float*)d_in[13];
    const float* bs2 = (const float*)d_in[14];
    float* out = (float*)d_out;
    float* ws  = (float*)d_ws;

    prep_kernel<<<73, 256, 0, stream>>>(Wk, bk, cq, cb, W1, W2, Wv, ws);
    main_kernel<<<NBLK, 256, 0, stream>>>(x, b1, b2, bv, ws, out);
    chart_kernel<<<NBLK, 256, 0, stream>>>(cb, Ws1, bs1, Ws2, bs2, ws, out, ws + WS_PART);
    fin_kernel<<<1, 256, 0, stream>>>(ws + WS_PART, out);
}